// Round 1
// baseline (557.299 us; speedup 1.0000x reference)
//
#include <hip/hip_runtime.h>
#include <hip/hip_bf16.h>
#include <cstdint>
#include <cstddef>

#define SEQ 2048
#define DM  1024

typedef __attribute__((ext_vector_type(8))) __bf16 bf16x8;
typedef __attribute__((ext_vector_type(4))) float  f32x4;
using bf16 = __hip_bfloat16;

// ---------------------------------------------------------------- helpers
__device__ __forceinline__ void gload_lds16(const bf16* g, bf16* l) {
  __builtin_amdgcn_global_load_lds((const __attribute__((address_space(1))) void*)g,
                                   (__attribute__((address_space(3))) void*)l,
                                   16, 0, 0);
}

// ---------------------------------------------------------------- transpose fp32(KxN) -> bf16(NxK)
__global__ void transpose_to_bf16(const float* __restrict__ in, bf16* __restrict__ out,
                                  int K, int N) {
  __shared__ float tile[32][33];
  const int k0 = blockIdx.y * 32, n0 = blockIdx.x * 32;
  const int tx = threadIdx.x, ty = threadIdx.y;
#pragma unroll
  for (int i = ty; i < 32; i += 8)
    tile[i][tx] = in[(size_t)(k0 + i) * N + n0 + tx];
  __syncthreads();
#pragma unroll
  for (int i = ty; i < 32; i += 8)
    out[(size_t)(n0 + i) * K + k0 + tx] = __float2bfloat16(tile[tx][i]);
}

// ---------------------------------------------------------------- layernorm fp32 row -> bf16
__global__ void ln_to_bf16(const float* __restrict__ x, const float* __restrict__ g,
                           const float* __restrict__ bt, bf16* __restrict__ out) {
  const int row = blockIdx.x;
  const float4 v = ((const float4*)(x + (size_t)row * DM))[threadIdx.x];
  float s  = v.x + v.y + v.z + v.w;
  float s2 = v.x * v.x + v.y * v.y + v.z * v.z + v.w * v.w;
#pragma unroll
  for (int o = 32; o > 0; o >>= 1) { s += __shfl_down(s, o); s2 += __shfl_down(s2, o); }
  __shared__ float red[8];
  const int wave = threadIdx.x >> 6, lane = threadIdx.x & 63;
  if (lane == 0) { red[wave] = s; red[4 + wave] = s2; }
  __syncthreads();
  s  = red[0] + red[1] + red[2] + red[3];
  s2 = red[4] + red[5] + red[6] + red[7];
  const float mu  = s * (1.f / DM);
  const float var = s2 * (1.f / DM) - mu * mu;
  const float r   = rsqrtf(var + 1e-5f);
  const float4 gv = ((const float4*)g)[threadIdx.x];
  const float4 bv = ((const float4*)bt)[threadIdx.x];
  bf16* o = out + (size_t)row * DM + threadIdx.x * 4;
  o[0] = __float2bfloat16((v.x - mu) * r * gv.x + bv.x);
  o[1] = __float2bfloat16((v.y - mu) * r * gv.y + bv.y);
  o[2] = __float2bfloat16((v.z - mu) * r * gv.z + bv.z);
  o[3] = __float2bfloat16((v.w - mu) * r * gv.w + bv.w);
}

// ---------------------------------------------------------------- GEMM: C = A(MxK) @ Bt(NxK)^T + bias, fused epilogue
enum { EP_BF16 = 0, EP_GELU = 1, EP_RESID = 2 };

template <int MODE>
__global__ void gemm_bt(const bf16* __restrict__ A, const bf16* __restrict__ Bt,
                        const float* __restrict__ bias, const float* __restrict__ resid,
                        float* __restrict__ Cf, bf16* __restrict__ Cb,
                        int M, int N, int K) {
  __shared__ __attribute__((aligned(16))) bf16 As[128 * 32];
  __shared__ __attribute__((aligned(16))) bf16 Bs[128 * 32];
  const int tid  = threadIdx.x;
  const int wave = tid >> 6, lane = tid & 63;
  const int l16 = lane & 15, lq = lane >> 4;
  const int m0 = blockIdx.x * 128, n0 = blockIdx.y * 128;
  const int wr = (wave >> 1) * 64, wc = (wave & 1) * 64;

  f32x4 acc[4][4];
#pragma unroll
  for (int i = 0; i < 4; i++)
#pragma unroll
    for (int j = 0; j < 4; j++) acc[i][j] = 0;

  // staging: chunk = tid -> row tid/4 (0..63), colchunk tid%4; second call rows 64..127
  const int srow = tid >> 2;
  const int scol = (tid & 3) * 8;
  const bf16* ga = A  + (size_t)(m0 + srow) * K + scol;
  const bf16* gb = Bt + (size_t)(n0 + srow) * K + scol;
  bf16* la = As + (size_t)wave * 512;   // wave-uniform LDS base, HW adds lane*16B
  bf16* lb = Bs + (size_t)wave * 512;

  for (int kt = 0; kt < K; kt += 32) {
    gload_lds16(ga + kt, la);
    gload_lds16(ga + (size_t)64 * K + kt, la + 2048);
    gload_lds16(gb + kt, lb);
    gload_lds16(gb + (size_t)64 * K + kt, lb + 2048);
    __syncthreads();
    bf16x8 af[4], bfr[4];
#pragma unroll
    for (int mi = 0; mi < 4; mi++)
      af[mi] = *(const bf16x8*)(As + (wr + mi * 16 + l16) * 32 + lq * 8);
#pragma unroll
    for (int ni = 0; ni < 4; ni++)
      bfr[ni] = *(const bf16x8*)(Bs + (wc + ni * 16 + l16) * 32 + lq * 8);
#pragma unroll
    for (int mi = 0; mi < 4; mi++)
#pragma unroll
      for (int ni = 0; ni < 4; ni++)
        acc[mi][ni] = __builtin_amdgcn_mfma_f32_16x16x32_bf16(af[mi], bfr[ni], acc[mi][ni], 0, 0, 0);
    __syncthreads();
  }

#pragma unroll
  for (int ni = 0; ni < 4; ni++) {
    const int col = n0 + wc + ni * 16 + l16;
    const float bb = bias[col];
#pragma unroll
    for (int mi = 0; mi < 4; mi++) {
#pragma unroll
      for (int r = 0; r < 4; r++) {
        const int row = m0 + wr + mi * 16 + lq * 4 + r;
        const size_t idx = (size_t)row * N + col;
        float v = acc[mi][ni][r] + bb;
        if (MODE == EP_BF16) {
          Cb[idx] = __float2bfloat16(v);
        } else if (MODE == EP_GELU) {
          v = 0.5f * v * (1.0f + erff(v * 0.70710678118654752f));
          Cb[idx] = __float2bfloat16(v);
        } else {
          Cf[idx] = resid[idx] + v;
        }
      }
    }
  }
}

// ---------------------------------------------------------------- flash attention (causal), bf16 in/out
// grid: (T/64, H, B); block 256 = 4 waves, each wave owns 16 query rows.
__global__ void flash_attn(const bf16* __restrict__ qkv, bf16* __restrict__ out) {
  const int qb = blockIdx.x, h = blockIdx.y, b = blockIdx.z;
  const int tid = threadIdx.x;
  const int wave = tid >> 6, lane = tid & 63;
  const int l16 = lane & 15, lq = lane >> 4;

  const size_t base = (size_t)b * SEQ * 3072;
  const bf16* Qg = qkv + base + (size_t)h * 64;
  const bf16* Kg = qkv + base + 1024 + (size_t)h * 64;
  const bf16* Vg = qkv + base + 2048 + (size_t)h * 64;

  __shared__ __attribute__((aligned(16))) bf16 Qs[64][72];
  __shared__ __attribute__((aligned(16))) bf16 Ks[32][72];
  __shared__ __attribute__((aligned(16))) bf16 VTs[64][48];
  __shared__ __attribute__((aligned(16))) bf16 Ps[4][16][32];

  const int q0 = qb * 64;
  {  // Q tile: thread -> row tid/4, cols (tid&3)*16 .. +15
    const int r = tid >> 2, c = (tid & 3) * 16;
    const bf16* src = Qg + (size_t)(q0 + r) * 3072 + c;
    *(uint4*)(&Qs[r][c])     = *(const uint4*)(src);
    *(uint4*)(&Qs[r][c + 8]) = *(const uint4*)(src + 8);
  }

  f32x4 oacc[4];
#pragma unroll
  for (int i = 0; i < 4; i++) oacc[i] = 0;
  float m_run[4], l_run[4];
#pragma unroll
  for (int r = 0; r < 4; r++) { m_run[r] = -1e30f; l_run[r] = 0.f; }

  const int nkb = (q0 + 64) >> 5;  // key blocks of 32 (causal bound)
  for (int kb = 0; kb < nkb; ++kb) {
    __syncthreads();
    {  // stage K rows + V transposed
      const int kr = tid >> 3, c = (tid & 7) * 8;
      *(uint4*)(&Ks[kr][c]) = *(const uint4*)(Kg + (size_t)(kb * 32 + kr) * 3072 + c);
      const bf16* vs = Vg + (size_t)(kb * 32 + kr) * 3072 + c;
      unsigned short tmp[8];
      *(ushort4*)(tmp)     = *(const ushort4*)(vs);
      *(ushort4*)(tmp + 4) = *(const ushort4*)(vs + 4);
      unsigned short* vt = (unsigned short*)&VTs[0][0];
#pragma unroll
      for (int i = 0; i < 8; i++) vt[(size_t)(c + i) * 48 + kr] = tmp[i];
    }
    __syncthreads();

    // S = Q K^T for this wave's 16 rows x 32 keys
    f32x4 sacc[2];
    sacc[0] = 0; sacc[1] = 0;
    const bf16x8 qf0 = *(const bf16x8*)(&Qs[wave * 16 + l16][lq * 8]);
    const bf16x8 qf1 = *(const bf16x8*)(&Qs[wave * 16 + l16][32 + lq * 8]);
#pragma unroll
    for (int nt = 0; nt < 2; nt++) {
      const bf16x8 kf0 = *(const bf16x8*)(&Ks[nt * 16 + l16][lq * 8]);
      const bf16x8 kf1 = *(const bf16x8*)(&Ks[nt * 16 + l16][32 + lq * 8]);
      sacc[nt] = __builtin_amdgcn_mfma_f32_16x16x32_bf16(qf0, kf0, sacc[nt], 0, 0, 0);
      sacc[nt] = __builtin_amdgcn_mfma_f32_16x16x32_bf16(qf1, kf1, sacc[nt], 0, 0, 0);
    }

    // online softmax; C-layout: row = lq*4+r, col = nt*16+l16
    float p0[4], p1[4];
#pragma unroll
    for (int r = 0; r < 4; r++) {
      const int qrow = q0 + wave * 16 + lq * 4 + r;
      float s0 = sacc[0][r] * 0.125f;
      float s1 = sacc[1][r] * 0.125f;
      if (kb * 32 + l16 > qrow)      s0 = -1e30f;
      if (kb * 32 + 16 + l16 > qrow) s1 = -1e30f;
      float mx = fmaxf(s0, s1);
      mx = fmaxf(mx, __shfl_xor(mx, 1));
      mx = fmaxf(mx, __shfl_xor(mx, 2));
      mx = fmaxf(mx, __shfl_xor(mx, 4));
      mx = fmaxf(mx, __shfl_xor(mx, 8));
      const float mnew = fmaxf(m_run[r], mx);
      const float alpha = __expf(m_run[r] - mnew);
      const float e0 = __expf(s0 - mnew);
      const float e1 = __expf(s1 - mnew);
      float rs = e0 + e1;
      rs += __shfl_xor(rs, 1);
      rs += __shfl_xor(rs, 2);
      rs += __shfl_xor(rs, 4);
      rs += __shfl_xor(rs, 8);
      l_run[r] = l_run[r] * alpha + rs;
      m_run[r] = mnew;
      p0[r] = e0; p1[r] = e1;
#pragma unroll
      for (int dt = 0; dt < 4; dt++) oacc[dt][r] *= alpha;
    }

    // P (C-layout) -> LDS -> A-layout fragment (wave-private scratch)
#pragma unroll
    for (int r = 0; r < 4; r++) {
      Ps[wave][lq * 4 + r][l16]      = __float2bfloat16(p0[r]);
      Ps[wave][lq * 4 + r][16 + l16] = __float2bfloat16(p1[r]);
    }
    const bf16x8 pf = *(const bf16x8*)(&Ps[wave][l16][lq * 8]);
#pragma unroll
    for (int dt = 0; dt < 4; dt++) {
      const bf16x8 vf = *(const bf16x8*)(&VTs[dt * 16 + l16][lq * 8]);
      oacc[dt] = __builtin_amdgcn_mfma_f32_16x16x32_bf16(pf, vf, oacc[dt], 0, 0, 0);
    }
  }

#pragma unroll
  for (int dt = 0; dt < 4; dt++)
#pragma unroll
    for (int r = 0; r < 4; r++) {
      const int qrow = q0 + wave * 16 + lq * 4 + r;
      const float v = oacc[dt][r] / l_run[r];
      out[(size_t)(b * SEQ + qrow) * DM + h * 64 + dt * 16 + l16] = __float2bfloat16(v);
    }
}

// ---------------------------------------------------------------- launch
extern "C" void kernel_launch(void* const* d_in, const int* in_sizes, int n_in,
                              void* d_out, int out_size, void* d_ws, size_t ws_size,
                              hipStream_t stream) {
  const float* x     = (const float*)d_in[0];
  const float* w_qkv = (const float*)d_in[1];
  const float* b_qkv = (const float*)d_in[2];
  const float* w_fc  = (const float*)d_in[3];
  const float* b_fc  = (const float*)d_in[4];
  const float* ln1_g = (const float*)d_in[5];
  const float* ln1_b = (const float*)d_in[6];
  const float* ln2_g = (const float*)d_in[7];
  const float* ln2_b = (const float*)d_in[8];
  const float* w1    = (const float*)d_in[9];
  const float* b1    = (const float*)d_in[10];
  const float* w2    = (const float*)d_in[11];
  const float* b2    = (const float*)d_in[12];
  float* out = (float*)d_out;

  char* ws    = (char*)d_ws;
  float* x2   = (float*)(ws);                       // 16 MB fp32 post-attn residual
  bf16* big   = (bf16*)(ws + (size_t)(16 << 20));   // 32 MB: qkv (24MB) then fc1 out (32MB)
  bf16* small = (bf16*)(ws + (size_t)(48 << 20));   // 8 MB: h1 / attn-out / h2
  bf16* wT    = (bf16*)(ws + (size_t)(56 << 20));   // 8 MB: transposed weight scratch

  const dim3 tb(32, 8);

  // LN1: x -> h1 (bf16)
  ln_to_bf16<<<dim3(4096), dim3(256), 0, stream>>>(x, ln1_g, ln1_b, small);
  // w_qkv^T (1024x3072 -> 3072x1024)
  transpose_to_bf16<<<dim3(96, 32), tb, 0, stream>>>(w_qkv, wT, 1024, 3072);
  // qkv = h1 @ w_qkv + b_qkv  (bf16 out)
  gemm_bt<EP_BF16><<<dim3(32, 24), dim3(256), 0, stream>>>(
      small, wT, b_qkv, nullptr, nullptr, big, 4096, 3072, 1024);
  // attention -> attn (bf16, reuse small)
  flash_attn<<<dim3(32, 16, 2), dim3(256), 0, stream>>>(big, small);
  // w_fc^T
  transpose_to_bf16<<<dim3(32, 32), tb, 0, stream>>>(w_fc, wT, 1024, 1024);
  // x2 = x + attn @ w_fc + b_fc  (fp32)
  gemm_bt<EP_RESID><<<dim3(32, 8), dim3(256), 0, stream>>>(
      small, wT, b_fc, x, x2, nullptr, 4096, 1024, 1024);
  // LN2: x2 -> h2 (bf16, reuse small)
  ln_to_bf16<<<dim3(4096), dim3(256), 0, stream>>>(x2, ln2_g, ln2_b, small);
  // w1^T (1024x4096 -> 4096x1024)
  transpose_to_bf16<<<dim3(128, 32), tb, 0, stream>>>(w1, wT, 1024, 4096);
  // fc1 = gelu(h2 @ w1 + b1) (bf16, reuse big)
  gemm_bt<EP_GELU><<<dim3(32, 32), dim3(256), 0, stream>>>(
      small, wT, b1, nullptr, nullptr, big, 4096, 4096, 1024);
  // w2^T (4096x1024 -> 1024x4096)
  transpose_to_bf16<<<dim3(32, 128), tb, 0, stream>>>(w2, wT, 4096, 1024);
  // out = x2 + fc1 @ w2 + b2 (fp32)
  gemm_bt<EP_RESID><<<dim3(32, 8), dim3(256), 0, stream>>>(
      big, wT, b2, x2, out, nullptr, 4096, 1024, 4096);
}

// Round 2
// 484.429 us; speedup vs baseline: 1.1504x; 1.1504x over previous
//
#include <hip/hip_runtime.h>
#include <hip/hip_bf16.h>
#include <cstdint>
#include <cstddef>

#define SEQ 2048
#define DM  1024

typedef __attribute__((ext_vector_type(8))) __bf16 bf16x8;
typedef __attribute__((ext_vector_type(4))) float  f32x4;
using bf16 = __hip_bfloat16;

// ---------------------------------------------------------------- helpers
__device__ __forceinline__ void gload_lds16(const bf16* g, bf16* l) {
  __builtin_amdgcn_global_load_lds((const __attribute__((address_space(1))) void*)g,
                                   (__attribute__((address_space(3))) void*)l,
                                   16, 0, 0);
}

// ---------------------------------------------------------------- transpose fp32(KxN) -> bf16(NxK)
__global__ void transpose_to_bf16(const float* __restrict__ in, bf16* __restrict__ out,
                                  int K, int N) {
  __shared__ float tile[32][33];
  const int k0 = blockIdx.y * 32, n0 = blockIdx.x * 32;
  const int tx = threadIdx.x, ty = threadIdx.y;
#pragma unroll
  for (int i = ty; i < 32; i += 8)
    tile[i][tx] = in[(size_t)(k0 + i) * N + n0 + tx];
  __syncthreads();
#pragma unroll
  for (int i = ty; i < 32; i += 8)
    out[(size_t)(n0 + i) * K + k0 + tx] = __float2bfloat16(tile[tx][i]);
}

// ---------------------------------------------------------------- layernorm fp32 row -> bf16
__global__ void ln_to_bf16(const float* __restrict__ x, const float* __restrict__ g,
                           const float* __restrict__ bt, bf16* __restrict__ out) {
  const int row = blockIdx.x;
  const float4 v = ((const float4*)(x + (size_t)row * DM))[threadIdx.x];
  float s  = v.x + v.y + v.z + v.w;
  float s2 = v.x * v.x + v.y * v.y + v.z * v.z + v.w * v.w;
#pragma unroll
  for (int o = 32; o > 0; o >>= 1) { s += __shfl_down(s, o); s2 += __shfl_down(s2, o); }
  __shared__ float red[8];
  const int wave = threadIdx.x >> 6, lane = threadIdx.x & 63;
  if (lane == 0) { red[wave] = s; red[4 + wave] = s2; }
  __syncthreads();
  s  = red[0] + red[1] + red[2] + red[3];
  s2 = red[4] + red[5] + red[6] + red[7];
  const float mu  = s * (1.f / DM);
  const float var = s2 * (1.f / DM) - mu * mu;
  const float r   = rsqrtf(var + 1e-5f);
  const float4 gv = ((const float4*)g)[threadIdx.x];
  const float4 bv = ((const float4*)bt)[threadIdx.x];
  bf16* o = out + (size_t)row * DM + threadIdx.x * 4;
  o[0] = __float2bfloat16((v.x - mu) * r * gv.x + bv.x);
  o[1] = __float2bfloat16((v.y - mu) * r * gv.y + bv.y);
  o[2] = __float2bfloat16((v.z - mu) * r * gv.z + bv.z);
  o[3] = __float2bfloat16((v.w - mu) * r * gv.w + bv.w);
}

// ---------------------------------------------------------------- GEMM: C = A(MxK) @ Bt(NxK)^T + bias, fused epilogue
enum { EP_BF16 = 0, EP_GELU = 1, EP_RESID = 2 };

template <int MODE>
__global__ void gemm_bt(const bf16* __restrict__ A, const bf16* __restrict__ Bt,
                        const float* __restrict__ bias, const float* __restrict__ resid,
                        float* __restrict__ Cf, bf16* __restrict__ Cb,
                        int M, int N, int K) {
  __shared__ __attribute__((aligned(16))) bf16 As[128 * 32];
  __shared__ __attribute__((aligned(16))) bf16 Bs[128 * 32];
  const int tid  = threadIdx.x;
  const int wave = tid >> 6, lane = tid & 63;
  const int l16 = lane & 15, lq = lane >> 4;
  const int m0 = blockIdx.x * 128, n0 = blockIdx.y * 128;
  const int wr = (wave >> 1) * 64, wc = (wave & 1) * 64;

  f32x4 acc[4][4];
#pragma unroll
  for (int i = 0; i < 4; i++)
#pragma unroll
    for (int j = 0; j < 4; j++) acc[i][j] = 0;

  const int srow = tid >> 2;
  const int scol = (tid & 3) * 8;
  const bf16* ga = A  + (size_t)(m0 + srow) * K + scol;
  const bf16* gb = Bt + (size_t)(n0 + srow) * K + scol;
  bf16* la = As + (size_t)wave * 512;
  bf16* lb = Bs + (size_t)wave * 512;

  for (int kt = 0; kt < K; kt += 32) {
    gload_lds16(ga + kt, la);
    gload_lds16(ga + (size_t)64 * K + kt, la + 2048);
    gload_lds16(gb + kt, lb);
    gload_lds16(gb + (size_t)64 * K + kt, lb + 2048);
    __syncthreads();
    bf16x8 af[4], bfr[4];
#pragma unroll
    for (int mi = 0; mi < 4; mi++)
      af[mi] = *(const bf16x8*)(As + (wr + mi * 16 + l16) * 32 + lq * 8);
#pragma unroll
    for (int ni = 0; ni < 4; ni++)
      bfr[ni] = *(const bf16x8*)(Bs + (wc + ni * 16 + l16) * 32 + lq * 8);
#pragma unroll
    for (int mi = 0; mi < 4; mi++)
#pragma unroll
      for (int ni = 0; ni < 4; ni++)
        acc[mi][ni] = __builtin_amdgcn_mfma_f32_16x16x32_bf16(af[mi], bfr[ni], acc[mi][ni], 0, 0, 0);
    __syncthreads();
  }

#pragma unroll
  for (int ni = 0; ni < 4; ni++) {
    const int col = n0 + wc + ni * 16 + l16;
    const float bb = bias[col];
#pragma unroll
    for (int mi = 0; mi < 4; mi++) {
#pragma unroll
      for (int r = 0; r < 4; r++) {
        const int row = m0 + wr + mi * 16 + lq * 4 + r;
        const size_t idx = (size_t)row * N + col;
        float v = acc[mi][ni][r] + bb;
        if (MODE == EP_BF16) {
          Cb[idx] = __float2bfloat16(v);
        } else if (MODE == EP_GELU) {
          v = 0.5f * v * (1.0f + erff(v * 0.70710678118654752f));
          Cb[idx] = __float2bfloat16(v);
        } else {
          Cf[idx] = resid[idx] + v;
        }
      }
    }
  }
}

// ---------------------------------------------------------------- flash attention v2 (causal)
// Single-barrier double-buffered pipeline. K-tile = 64.
// grid (32,16,2), qb = 31-blockIdx.x (LPT). 4 waves, each owns 16 q-rows.
#define SCALE_LOG2 0.18033688011112042f  /* 0.125 * log2(e) */

__global__ void flash_attn(const bf16* __restrict__ qkv, bf16* __restrict__ out) {
  const int qb = (int)gridDim.x - 1 - blockIdx.x;  // LPT: longest blocks first
  const int h = blockIdx.y, b = blockIdx.z;
  const int tid = threadIdx.x;
  const int w = tid >> 6, lane = tid & 63;
  const int l16 = lane & 15, lq = lane >> 4;

  const size_t base = (size_t)b * SEQ * 3072;
  const bf16* Qg = qkv + base + (size_t)h * 64;
  const bf16* Kg = qkv + base + 1024 + (size_t)h * 64;
  const ushort* Vg = (const ushort*)(qkv + base + 2048 + (size_t)h * 64);

  // 72-elem row stride: row*36 dwords -> 4*row mod 32 spreads bank starts.
  __shared__ __attribute__((aligned(16))) bf16 Qs[64][72];
  __shared__ __attribute__((aligned(16))) bf16 Ks[2][64][72];
  __shared__ __attribute__((aligned(16))) bf16 VTs[2][64 * 64];  // XOR-swizzled V^T
  __shared__ __attribute__((aligned(16))) bf16 Ps[4][16][72];

  const int q0 = qb * 64;
  const int nkb = qb + 1;  // number of 64-key tiles (causal)

  // ---- stage Q tile (once)
  {
    const int r = tid >> 2, c = (tid & 3) * 16;
    const bf16* src = Qg + (size_t)(q0 + r) * 3072 + c;
    *(uint4*)(&Qs[r][c])     = *(const uint4*)(src);
    *(uint4*)(&Qs[r][c + 8]) = *(const uint4*)(src + 8);
  }

  // staging geometry
  const int krow = tid >> 2, kcol = (tid & 3) * 16;           // K: row, 2x uint4
  const int vd = tid & 63, vc = tid >> 6;                     // V: strips (vc, vc+4) at col vd
  const int vsw0 = ((vc ^ (vd & 7)) * 8);                     // swizzled chunk offsets
  const int vsw1 = (((vc + 4) ^ (vd & 7)) * 8);

  uint4 kr0, kr1;
  ushort va[8], vb[8];

  // ---- prefetch tile 0 -> regs, write -> buf 0
  {
    const bf16* ks = Kg + (size_t)krow * 3072 + kcol;
    kr0 = *(const uint4*)(ks);
    kr1 = *(const uint4*)(ks + 8);
#pragma unroll
    for (int j = 0; j < 8; j++) va[j] = Vg[(size_t)(vc * 8 + j) * 3072 + vd];
#pragma unroll
    for (int j = 0; j < 8; j++) vb[j] = Vg[(size_t)((vc + 4) * 8 + j) * 3072 + vd];
    *(uint4*)(&Ks[0][krow][kcol])     = kr0;
    *(uint4*)(&Ks[0][krow][kcol + 8]) = kr1;
    uint4 wa, wb;
    wa.x = (uint)va[0] | ((uint)va[1] << 16); wa.y = (uint)va[2] | ((uint)va[3] << 16);
    wa.z = (uint)va[4] | ((uint)va[5] << 16); wa.w = (uint)va[6] | ((uint)va[7] << 16);
    wb.x = (uint)vb[0] | ((uint)vb[1] << 16); wb.y = (uint)vb[2] | ((uint)vb[3] << 16);
    wb.z = (uint)vb[4] | ((uint)vb[5] << 16); wb.w = (uint)vb[6] | ((uint)vb[7] << 16);
    *(uint4*)(&VTs[0][vd * 64 + vsw0]) = wa;
    *(uint4*)(&VTs[0][vd * 64 + vsw1]) = wb;
  }

  f32x4 oacc[4];
#pragma unroll
  for (int i = 0; i < 4; i++) oacc[i] = 0;
  float m_run[4], l_run[4];
#pragma unroll
  for (int r = 0; r < 4; r++) { m_run[r] = -1e30f; l_run[r] = 0.f; }

  bf16x8 qf0, qf1;
  bool qf_loaded = false;

  for (int kb = 0; kb < nkb; ++kb) {
    __syncthreads();  // buf[kb&1] visible to all waves
    const int cur = kb & 1;
    const bool more = (kb + 1 < nkb);

    // issue prefetch for tile kb+1 (latency overlapped with compute below)
    if (more) {
      const size_t koff = (size_t)((kb + 1) * 64);
      const bf16* ks = Kg + (koff + krow) * 3072 + kcol;
      kr0 = *(const uint4*)(ks);
      kr1 = *(const uint4*)(ks + 8);
#pragma unroll
      for (int j = 0; j < 8; j++) va[j] = Vg[(koff + vc * 8 + j) * 3072 + vd];
#pragma unroll
      for (int j = 0; j < 8; j++) vb[j] = Vg[(koff + (vc + 4) * 8 + j) * 3072 + vd];
    }

    if (!qf_loaded) {  // Q fragment, hoisted (constant over kb)
      qf0 = *(const bf16x8*)(&Qs[w * 16 + l16][lq * 8]);
      qf1 = *(const bf16x8*)(&Qs[w * 16 + l16][32 + lq * 8]);
      qf_loaded = true;
    }

    // ---- S = Q K^T : 4 ntiles x 2 k-halves
    f32x4 sacc[4];
#pragma unroll
    for (int nt = 0; nt < 4; nt++) sacc[nt] = 0;
#pragma unroll
    for (int nt = 0; nt < 4; nt++) {
      const bf16x8 kf0 = *(const bf16x8*)(&Ks[cur][nt * 16 + l16][lq * 8]);
      const bf16x8 kf1 = *(const bf16x8*)(&Ks[cur][nt * 16 + l16][32 + lq * 8]);
      sacc[nt] = __builtin_amdgcn_mfma_f32_16x16x32_bf16(qf0, kf0, sacc[nt], 0, 0, 0);
      sacc[nt] = __builtin_amdgcn_mfma_f32_16x16x32_bf16(qf1, kf1, sacc[nt], 0, 0, 0);
    }

    // ---- online softmax (log2 domain), C-layout: row=lq*4+r, col=nt*16+l16
    const bool diag = (kb == qb);
#pragma unroll
    for (int r = 0; r < 4; r++) {
      float sv[4];
#pragma unroll
      for (int nt = 0; nt < 4; nt++) sv[nt] = sacc[nt][r] * SCALE_LOG2;
      if (diag) {
        const int qr = w * 16 + lq * 4 + r;
#pragma unroll
        for (int nt = 0; nt < 4; nt++)
          if (nt * 16 + l16 > qr) sv[nt] = -1e30f;
      }
      float mx = fmaxf(fmaxf(sv[0], sv[1]), fmaxf(sv[2], sv[3]));
      mx = fmaxf(mx, __shfl_xor(mx, 1));
      mx = fmaxf(mx, __shfl_xor(mx, 2));
      mx = fmaxf(mx, __shfl_xor(mx, 4));
      mx = fmaxf(mx, __shfl_xor(mx, 8));
      const float mnew = fmaxf(m_run[r], mx);
      const float alpha = exp2f(m_run[r] - mnew);
      float e[4], rs;
#pragma unroll
      for (int nt = 0; nt < 4; nt++) e[nt] = exp2f(sv[nt] - mnew);
      rs = (e[0] + e[1]) + (e[2] + e[3]);
      rs += __shfl_xor(rs, 1);
      rs += __shfl_xor(rs, 2);
      rs += __shfl_xor(rs, 4);
      rs += __shfl_xor(rs, 8);
      l_run[r] = l_run[r] * alpha + rs;
      m_run[r] = mnew;
#pragma unroll
      for (int nt = 0; nt < 4; nt++)
        Ps[w][lq * 4 + r][nt * 16 + l16] = __float2bfloat16(e[nt]);
#pragma unroll
      for (int dt = 0; dt < 4; dt++) oacc[dt][r] *= alpha;
    }

    // ---- PV: P (A-layout via wave-private LDS round-trip), V^T swizzled
    const bf16x8 pf0 = *(const bf16x8*)(&Ps[w][l16][lq * 8]);
    const bf16x8 pf1 = *(const bf16x8*)(&Ps[w][l16][32 + lq * 8]);
    const int sw0 = (lq ^ (l16 & 7)) * 8;
    const int sw1 = ((4 + lq) ^ (l16 & 7)) * 8;
#pragma unroll
    for (int dt = 0; dt < 4; dt++) {
      const int d = dt * 16 + l16;
      const bf16x8 vf0 = *(const bf16x8*)(&VTs[cur][d * 64 + sw0]);
      const bf16x8 vf1 = *(const bf16x8*)(&VTs[cur][d * 64 + sw1]);
      oacc[dt] = __builtin_amdgcn_mfma_f32_16x16x32_bf16(pf0, vf0, oacc[dt], 0, 0, 0);
      oacc[dt] = __builtin_amdgcn_mfma_f32_16x16x32_bf16(pf1, vf1, oacc[dt], 0, 0, 0);
    }

    // ---- write prefetched tile kb+1 into the other buffer (no barrier:
    // that buffer was last read at iter kb-1, before the barrier above)
    if (more) {
      const int nxt = cur ^ 1;
      *(uint4*)(&Ks[nxt][krow][kcol])     = kr0;
      *(uint4*)(&Ks[nxt][krow][kcol + 8]) = kr1;
      uint4 wa, wb;
      wa.x = (uint)va[0] | ((uint)va[1] << 16); wa.y = (uint)va[2] | ((uint)va[3] << 16);
      wa.z = (uint)va[4] | ((uint)va[5] << 16); wa.w = (uint)va[6] | ((uint)va[7] << 16);
      wb.x = (uint)vb[0] | ((uint)vb[1] << 16); wb.y = (uint)vb[2] | ((uint)vb[3] << 16);
      wb.z = (uint)vb[4] | ((uint)vb[5] << 16); wb.w = (uint)vb[6] | ((uint)vb[7] << 16);
      *(uint4*)(&VTs[nxt][vd * 64 + vsw0]) = wa;
      *(uint4*)(&VTs[nxt][vd * 64 + vsw1]) = wb;
    }
  }

#pragma unroll
  for (int dt = 0; dt < 4; dt++)
#pragma unroll
    for (int r = 0; r < 4; r++) {
      const int qrow = q0 + w * 16 + lq * 4 + r;
      const float v = oacc[dt][r] / l_run[r];
      out[(size_t)(b * SEQ + qrow) * DM + h * 64 + dt * 16 + l16] = __float2bfloat16(v);
    }
}

// ---------------------------------------------------------------- launch
extern "C" void kernel_launch(void* const* d_in, const int* in_sizes, int n_in,
                              void* d_out, int out_size, void* d_ws, size_t ws_size,
                              hipStream_t stream) {
  const float* x     = (const float*)d_in[0];
  const float* w_qkv = (const float*)d_in[1];
  const float* b_qkv = (const float*)d_in[2];
  const float* w_fc  = (const float*)d_in[3];
  const float* b_fc  = (const float*)d_in[4];
  const float* ln1_g = (const float*)d_in[5];
  const float* ln1_b = (const float*)d_in[6];
  const float* ln2_g = (const float*)d_in[7];
  const float* ln2_b = (const float*)d_in[8];
  const float* w1    = (const float*)d_in[9];
  const float* b1    = (const float*)d_in[10];
  const float* w2    = (const float*)d_in[11];
  const float* b2    = (const float*)d_in[12];
  float* out = (float*)d_out;

  char* ws    = (char*)d_ws;
  float* x2   = (float*)(ws);                       // 16 MB fp32 post-attn residual
  bf16* big   = (bf16*)(ws + (size_t)(16 << 20));   // 32 MB: qkv (24MB) then fc1 out (32MB)
  bf16* small = (bf16*)(ws + (size_t)(48 << 20));   // 8 MB: h1 / attn-out / h2
  bf16* wT    = (bf16*)(ws + (size_t)(56 << 20));   // 8 MB: transposed weight scratch

  const dim3 tb(32, 8);

  ln_to_bf16<<<dim3(4096), dim3(256), 0, stream>>>(x, ln1_g, ln1_b, small);
  transpose_to_bf16<<<dim3(96, 32), tb, 0, stream>>>(w_qkv, wT, 1024, 3072);
  gemm_bt<EP_BF16><<<dim3(32, 24), dim3(256), 0, stream>>>(
      small, wT, b_qkv, nullptr, nullptr, big, 4096, 3072, 1024);
  flash_attn<<<dim3(32, 16, 2), dim3(256), 0, stream>>>(big, small);
  transpose_to_bf16<<<dim3(32, 32), tb, 0, stream>>>(w_fc, wT, 1024, 1024);
  gemm_bt<EP_RESID><<<dim3(32, 8), dim3(256), 0, stream>>>(
      small, wT, b_fc, x, x2, nullptr, 4096, 1024, 1024);
  ln_to_bf16<<<dim3(4096), dim3(256), 0, stream>>>(x2, ln2_g, ln2_b, small);
  transpose_to_bf16<<<dim3(128, 32), tb, 0, stream>>>(w1, wT, 1024, 4096);
  gemm_bt<EP_GELU><<<dim3(32, 32), dim3(256), 0, stream>>>(
      small, wT, b1, nullptr, nullptr, big, 4096, 4096, 1024);
  transpose_to_bf16<<<dim3(32, 128), tb, 0, stream>>>(w2, wT, 4096, 1024);
  gemm_bt<EP_RESID><<<dim3(32, 8), dim3(256), 0, stream>>>(
      big, wT, b2, x2, out, nullptr, 4096, 1024, 4096);
}

// Round 3
// 412.056 us; speedup vs baseline: 1.3525x; 1.1756x over previous
//
#include <hip/hip_runtime.h>
#include <hip/hip_bf16.h>
#include <cstdint>
#include <cstddef>

#define SEQ 2048
#define DM  1024

typedef __attribute__((ext_vector_type(8))) __bf16 bf16x8;
typedef __attribute__((ext_vector_type(4))) float  f32x4;
using bf16 = __hip_bfloat16;

// ---------------------------------------------------------------- helpers
__device__ __forceinline__ void gload_lds16(const bf16* g, bf16* l) {
  __builtin_amdgcn_global_load_lds((const __attribute__((address_space(1))) void*)g,
                                   (__attribute__((address_space(3))) void*)l,
                                   16, 0, 0);
}

// ---------------------------------------------------------------- transpose fp32(KxN) -> bf16(NxK)
__global__ void transpose_to_bf16(const float* __restrict__ in, bf16* __restrict__ out,
                                  int K, int N) {
  __shared__ float tile[32][33];
  const int k0 = blockIdx.y * 32, n0 = blockIdx.x * 32;
  const int tx = threadIdx.x, ty = threadIdx.y;
#pragma unroll
  for (int i = ty; i < 32; i += 8)
    tile[i][tx] = in[(size_t)(k0 + i) * N + n0 + tx];
  __syncthreads();
#pragma unroll
  for (int i = ty; i < 32; i += 8)
    out[(size_t)(n0 + i) * K + k0 + tx] = __float2bfloat16(tile[tx][i]);
}

// ---------------------------------------------------------------- layernorm fp32 row -> bf16
__global__ void ln_to_bf16(const float* __restrict__ x, const float* __restrict__ g,
                           const float* __restrict__ bt, bf16* __restrict__ out) {
  const int row = blockIdx.x;
  const float4 v = ((const float4*)(x + (size_t)row * DM))[threadIdx.x];
  float s  = v.x + v.y + v.z + v.w;
  float s2 = v.x * v.x + v.y * v.y + v.z * v.z + v.w * v.w;
#pragma unroll
  for (int o = 32; o > 0; o >>= 1) { s += __shfl_down(s, o); s2 += __shfl_down(s2, o); }
  __shared__ float red[8];
  const int wave = threadIdx.x >> 6, lane = threadIdx.x & 63;
  if (lane == 0) { red[wave] = s; red[4 + wave] = s2; }
  __syncthreads();
  s  = red[0] + red[1] + red[2] + red[3];
  s2 = red[4] + red[5] + red[6] + red[7];
  const float mu  = s * (1.f / DM);
  const float var = s2 * (1.f / DM) - mu * mu;
  const float r   = rsqrtf(var + 1e-5f);
  const float4 gv = ((const float4*)g)[threadIdx.x];
  const float4 bv = ((const float4*)bt)[threadIdx.x];
  bf16* o = out + (size_t)row * DM + threadIdx.x * 4;
  o[0] = __float2bfloat16((v.x - mu) * r * gv.x + bv.x);
  o[1] = __float2bfloat16((v.y - mu) * r * gv.y + bv.y);
  o[2] = __float2bfloat16((v.z - mu) * r * gv.z + bv.z);
  o[3] = __float2bfloat16((v.w - mu) * r * gv.w + bv.w);
}

// ---------------------------------------------------------------- GEMM: C = A(MxK) @ Bt(NxK)^T + bias, fused epilogue
enum { EP_BF16 = 0, EP_GELU = 1, EP_RESID = 2 };

template <int MODE>
__global__ void gemm_bt(const bf16* __restrict__ A, const bf16* __restrict__ Bt,
                        const float* __restrict__ bias, const float* __restrict__ resid,
                        float* __restrict__ Cf, bf16* __restrict__ Cb,
                        int M, int N, int K) {
  __shared__ __attribute__((aligned(16))) bf16 As[128 * 32];
  __shared__ __attribute__((aligned(16))) bf16 Bs[128 * 32];
  const int tid  = threadIdx.x;
  const int wave = tid >> 6, lane = tid & 63;
  const int l16 = lane & 15, lq = lane >> 4;
  const int m0 = blockIdx.x * 128, n0 = blockIdx.y * 128;
  const int wr = (wave >> 1) * 64, wc = (wave & 1) * 64;

  f32x4 acc[4][4];
#pragma unroll
  for (int i = 0; i < 4; i++)
#pragma unroll
    for (int j = 0; j < 4; j++) acc[i][j] = 0;

  const int srow = tid >> 2;
  const int scol = (tid & 3) * 8;
  const bf16* ga = A  + (size_t)(m0 + srow) * K + scol;
  const bf16* gb = Bt + (size_t)(n0 + srow) * K + scol;
  bf16* la = As + (size_t)wave * 512;
  bf16* lb = Bs + (size_t)wave * 512;

  for (int kt = 0; kt < K; kt += 32) {
    gload_lds16(ga + kt, la);
    gload_lds16(ga + (size_t)64 * K + kt, la + 2048);
    gload_lds16(gb + kt, lb);
    gload_lds16(gb + (size_t)64 * K + kt, lb + 2048);
    __syncthreads();
    bf16x8 af[4], bfr[4];
#pragma unroll
    for (int mi = 0; mi < 4; mi++)
      af[mi] = *(const bf16x8*)(As + (wr + mi * 16 + l16) * 32 + lq * 8);
#pragma unroll
    for (int ni = 0; ni < 4; ni++)
      bfr[ni] = *(const bf16x8*)(Bs + (wc + ni * 16 + l16) * 32 + lq * 8);
#pragma unroll
    for (int mi = 0; mi < 4; mi++)
#pragma unroll
      for (int ni = 0; ni < 4; ni++)
        acc[mi][ni] = __builtin_amdgcn_mfma_f32_16x16x32_bf16(af[mi], bfr[ni], acc[mi][ni], 0, 0, 0);
    __syncthreads();
  }

#pragma unroll
  for (int ni = 0; ni < 4; ni++) {
    const int col = n0 + wc + ni * 16 + l16;
    const float bb = bias[col];
#pragma unroll
    for (int mi = 0; mi < 4; mi++) {
#pragma unroll
      for (int r = 0; r < 4; r++) {
        const int row = m0 + wr + mi * 16 + lq * 4 + r;
        const size_t idx = (size_t)row * N + col;
        float v = acc[mi][ni][r] + bb;
        if (MODE == EP_BF16) {
          Cb[idx] = __float2bfloat16(v);
        } else if (MODE == EP_GELU) {
          v = 0.5f * v * (1.0f + erff(v * 0.70710678118654752f));
          Cb[idx] = __float2bfloat16(v);
        } else {
          Cf[idx] = resid[idx] + v;
        }
      }
    }
  }
}

// ---------------------------------------------------------------- flash attention v3 (causal)
// Flat 1024-block grid with work-uniform swizzle: every stride-256 set of
// blocks (co-resident on one CU) gets qb in {a, 15-a, 16+a, 31-a} -> exactly
// 70 k-tile iterations per CU. No-max softmax (scores bounded; clamp 88),
// l accumulated per-lane, reduced once in the epilogue.
// Single-buffer K/V in LDS (35 KB -> 4 blocks/CU) + register-held prefetch.
#define SCALE_LOG2 0.18033688011112042f  /* 0.125 * log2(e) */

__global__ void flash_attn(const bf16* __restrict__ qkv, bf16* __restrict__ out) {
  const int id = blockIdx.x;
  const int a  = id & 7;
  const int h  = (id >> 3) & 15;
  const int b  = (id >> 7) & 1;
  const int m  = (id >> 8) & 3;
  const int qb = a ^ (((m & 1) * 15) | ((m & 2) << 3));  // {a,15-a,16+a,31-a}

  const int tid = threadIdx.x;
  const int w = tid >> 6, lane = tid & 63;
  const int l16 = lane & 15, lq = lane >> 4;

  const size_t base = (size_t)b * SEQ * 3072;
  const bf16* Qg = qkv + base + (size_t)h * 64;
  const bf16* Kg = qkv + base + 1024 + (size_t)h * 64;
  const ushort* Vg = (const ushort*)(qkv + base + 2048 + (size_t)h * 64);

  __shared__ __attribute__((aligned(16))) bf16 Qs[64][72];
  __shared__ __attribute__((aligned(16))) bf16 Ks[64][72];
  __shared__ __attribute__((aligned(16))) bf16 VTs[64 * 64];  // XOR-swizzled V^T
  __shared__ __attribute__((aligned(16))) bf16 Ps[4][16][72];

  const int q0 = qb * 64;
  const int nkb = qb + 1;

  // staging geometry
  const int krow = tid >> 2, kcol = (tid & 3) * 16;
  const int vd = tid & 63, vc = tid >> 6;
  const int vsw0 = ((vc ^ (vd & 7)) * 8);
  const int vsw1 = (((vc + 4) ^ (vd & 7)) * 8);

  // ---- stage Q tile + prefetch tile 0 and write it (pre-barrier)
  {
    const int r = tid >> 2, c = (tid & 3) * 16;
    const bf16* src = Qg + (size_t)(q0 + r) * 3072 + c;
    *(uint4*)(&Qs[r][c])     = *(const uint4*)(src);
    *(uint4*)(&Qs[r][c + 8]) = *(const uint4*)(src + 8);

    const bf16* ks = Kg + (size_t)krow * 3072 + kcol;
    const uint4 k0 = *(const uint4*)(ks);
    const uint4 k1 = *(const uint4*)(ks + 8);
    ushort va[8], vb[8];
#pragma unroll
    for (int j = 0; j < 8; j++) va[j] = Vg[(size_t)(vc * 8 + j) * 3072 + vd];
#pragma unroll
    for (int j = 0; j < 8; j++) vb[j] = Vg[(size_t)((vc + 4) * 8 + j) * 3072 + vd];
    *(uint4*)(&Ks[krow][kcol])     = k0;
    *(uint4*)(&Ks[krow][kcol + 8]) = k1;
    uint4 wa, wb;
    wa.x = (uint)va[0] | ((uint)va[1] << 16); wa.y = (uint)va[2] | ((uint)va[3] << 16);
    wa.z = (uint)va[4] | ((uint)va[5] << 16); wa.w = (uint)va[6] | ((uint)va[7] << 16);
    wb.x = (uint)vb[0] | ((uint)vb[1] << 16); wb.y = (uint)vb[2] | ((uint)vb[3] << 16);
    wb.z = (uint)vb[4] | ((uint)vb[5] << 16); wb.w = (uint)vb[6] | ((uint)vb[7] << 16);
    *(uint4*)(&VTs[vd * 64 + vsw0]) = wa;
    *(uint4*)(&VTs[vd * 64 + vsw1]) = wb;
  }
  __syncthreads();

  // Q fragments (constant over kb)
  const bf16x8 qf0 = *(const bf16x8*)(&Qs[w * 16 + l16][lq * 8]);
  const bf16x8 qf1 = *(const bf16x8*)(&Qs[w * 16 + l16][32 + lq * 8]);

  f32x4 oacc[4];
#pragma unroll
  for (int i = 0; i < 4; i++) oacc[i] = 0;
  float lsum[4] = {0.f, 0.f, 0.f, 0.f};

  uint4 kr0, kr1;
  ushort va[8], vb[8];
  const int sw0 = (lq ^ (l16 & 7)) * 8;
  const int sw1 = ((4 + lq) ^ (l16 & 7)) * 8;

  for (int kb = 0; kb < nkb; ++kb) {
    const bool more = (kb + 1 < nkb);

    // issue prefetch for tile kb+1 (latency overlaps compute below)
    if (more) {
      const size_t koff = (size_t)((kb + 1) * 64);
      const bf16* ks = Kg + (koff + krow) * 3072 + kcol;
      kr0 = *(const uint4*)(ks);
      kr1 = *(const uint4*)(ks + 8);
#pragma unroll
      for (int j = 0; j < 8; j++) va[j] = Vg[(koff + vc * 8 + j) * 3072 + vd];
#pragma unroll
      for (int j = 0; j < 8; j++) vb[j] = Vg[(koff + (vc + 4) * 8 + j) * 3072 + vd];
    }

    // ---- S = Q K^T : 4 ntiles x 2 k-halves
    f32x4 sacc[4];
#pragma unroll
    for (int nt = 0; nt < 4; nt++) sacc[nt] = 0;
#pragma unroll
    for (int nt = 0; nt < 4; nt++) {
      const bf16x8 kf0 = *(const bf16x8*)(&Ks[nt * 16 + l16][lq * 8]);
      const bf16x8 kf1 = *(const bf16x8*)(&Ks[nt * 16 + l16][32 + lq * 8]);
      sacc[nt] = __builtin_amdgcn_mfma_f32_16x16x32_bf16(qf0, kf0, sacc[nt], 0, 0, 0);
      sacc[nt] = __builtin_amdgcn_mfma_f32_16x16x32_bf16(qf1, kf1, sacc[nt], 0, 0, 0);
    }

    // ---- no-max softmax: e = 2^(s*scale), per-lane l accumulation
    const bool diag = (kb == qb);
#pragma unroll
    for (int r = 0; r < 4; r++) {
      float e[4];
#pragma unroll
      for (int nt = 0; nt < 4; nt++) {
        float sv = sacc[nt][r] * SCALE_LOG2;
        sv = fminf(sv, 88.f);  // overflow guard (never binds for real data)
        if (diag && (nt * 16 + l16 > w * 16 + lq * 4 + r)) sv = -1e30f;
        e[nt] = exp2f(sv);
        Ps[w][lq * 4 + r][nt * 16 + l16] = __float2bfloat16(e[nt]);
      }
      lsum[r] += (e[0] + e[1]) + (e[2] + e[3]);
    }

    // ---- PV: P via wave-private LDS round-trip, V^T swizzled
    const bf16x8 pf0 = *(const bf16x8*)(&Ps[w][l16][lq * 8]);
    const bf16x8 pf1 = *(const bf16x8*)(&Ps[w][l16][32 + lq * 8]);
#pragma unroll
    for (int dt = 0; dt < 4; dt++) {
      const int d = dt * 16 + l16;
      const bf16x8 vf0 = *(const bf16x8*)(&VTs[d * 64 + sw0]);
      const bf16x8 vf1 = *(const bf16x8*)(&VTs[d * 64 + sw1]);
      oacc[dt] = __builtin_amdgcn_mfma_f32_16x16x32_bf16(pf0, vf0, oacc[dt], 0, 0, 0);
      oacc[dt] = __builtin_amdgcn_mfma_f32_16x16x32_bf16(pf1, vf1, oacc[dt], 0, 0, 0);
    }

    // ---- publish prefetched tile kb+1 (single buffer, two barriers)
    if (more) {
      __syncthreads();  // all reads of tile kb done
      *(uint4*)(&Ks[krow][kcol])     = kr0;
      *(uint4*)(&Ks[krow][kcol + 8]) = kr1;
      uint4 wa, wb;
      wa.x = (uint)va[0] | ((uint)va[1] << 16); wa.y = (uint)va[2] | ((uint)va[3] << 16);
      wa.z = (uint)va[4] | ((uint)va[5] << 16); wa.w = (uint)va[6] | ((uint)va[7] << 16);
      wb.x = (uint)vb[0] | ((uint)vb[1] << 16); wb.y = (uint)vb[2] | ((uint)vb[3] << 16);
      wb.z = (uint)vb[4] | ((uint)vb[5] << 16); wb.w = (uint)vb[6] | ((uint)vb[7] << 16);
      *(uint4*)(&VTs[vd * 64 + vsw0]) = wa;
      *(uint4*)(&VTs[vd * 64 + vsw1]) = wb;
      __syncthreads();  // writes visible
    }
  }

  // ---- epilogue: reduce l across the 16 l16-lanes, write O
#pragma unroll
  for (int r = 0; r < 4; r++) {
    float l = lsum[r];
    l += __shfl_xor(l, 1);
    l += __shfl_xor(l, 2);
    l += __shfl_xor(l, 4);
    l += __shfl_xor(l, 8);
    lsum[r] = 1.f / l;
  }
#pragma unroll
  for (int dt = 0; dt < 4; dt++)
#pragma unroll
    for (int r = 0; r < 4; r++) {
      const int qrow = q0 + w * 16 + lq * 4 + r;
      const float v = oacc[dt][r] * lsum[r];
      out[(size_t)(b * SEQ + qrow) * DM + h * 64 + dt * 16 + l16] = __float2bfloat16(v);
    }
}

// ---------------------------------------------------------------- launch
extern "C" void kernel_launch(void* const* d_in, const int* in_sizes, int n_in,
                              void* d_out, int out_size, void* d_ws, size_t ws_size,
                              hipStream_t stream) {
  const float* x     = (const float*)d_in[0];
  const float* w_qkv = (const float*)d_in[1];
  const float* b_qkv = (const float*)d_in[2];
  const float* w_fc  = (const float*)d_in[3];
  const float* b_fc  = (const float*)d_in[4];
  const float* ln1_g = (const float*)d_in[5];
  const float* ln1_b = (const float*)d_in[6];
  const float* ln2_g = (const float*)d_in[7];
  const float* ln2_b = (const float*)d_in[8];
  const float* w1    = (const float*)d_in[9];
  const float* b1    = (const float*)d_in[10];
  const float* w2    = (const float*)d_in[11];
  const float* b2    = (const float*)d_in[12];
  float* out = (float*)d_out;

  char* ws    = (char*)d_ws;
  float* x2   = (float*)(ws);                       // 16 MB fp32 post-attn residual
  bf16* big   = (bf16*)(ws + (size_t)(16 << 20));   // 32 MB: qkv (24MB) then fc1 out (32MB)
  bf16* small = (bf16*)(ws + (size_t)(48 << 20));   // 8 MB: h1 / attn-out / h2
  bf16* wT    = (bf16*)(ws + (size_t)(56 << 20));   // 8 MB: transposed weight scratch

  const dim3 tb(32, 8);

  ln_to_bf16<<<dim3(4096), dim3(256), 0, stream>>>(x, ln1_g, ln1_b, small);
  transpose_to_bf16<<<dim3(96, 32), tb, 0, stream>>>(w_qkv, wT, 1024, 3072);
  gemm_bt<EP_BF16><<<dim3(32, 24), dim3(256), 0, stream>>>(
      small, wT, b_qkv, nullptr, nullptr, big, 4096, 3072, 1024);
  flash_attn<<<dim3(1024), dim3(256), 0, stream>>>(big, small);
  transpose_to_bf16<<<dim3(32, 32), tb, 0, stream>>>(w_fc, wT, 1024, 1024);
  gemm_bt<EP_RESID><<<dim3(32, 8), dim3(256), 0, stream>>>(
      small, wT, b_fc, x, x2, nullptr, 4096, 1024, 1024);
  ln_to_bf16<<<dim3(4096), dim3(256), 0, stream>>>(x2, ln2_g, ln2_b, small);
  transpose_to_bf16<<<dim3(128, 32), tb, 0, stream>>>(w1, wT, 1024, 4096);
  gemm_bt<EP_GELU><<<dim3(32, 32), dim3(256), 0, stream>>>(
      small, wT, b1, nullptr, nullptr, big, 4096, 4096, 1024);
  transpose_to_bf16<<<dim3(32, 128), tb, 0, stream>>>(w2, wT, 4096, 1024);
  gemm_bt<EP_RESID><<<dim3(32, 8), dim3(256), 0, stream>>>(
      big, wT, b2, x2, out, nullptr, 4096, 1024, 4096);
}

// Round 4
// 384.300 us; speedup vs baseline: 1.4502x; 1.0722x over previous
//
#include <hip/hip_runtime.h>
#include <hip/hip_bf16.h>
#include <cstdint>
#include <cstddef>

#define SEQ 2048
#define DM  1024

typedef __attribute__((ext_vector_type(8))) __bf16 bf16x8;
typedef __attribute__((ext_vector_type(4))) float  f32x4;
using bf16 = __hip_bfloat16;

// ---------------------------------------------------------------- helpers
__device__ __forceinline__ void gload_lds16(const bf16* g, bf16* l) {
  __builtin_amdgcn_global_load_lds((const __attribute__((address_space(1))) void*)g,
                                   (__attribute__((address_space(3))) void*)l,
                                   16, 0, 0);
}

// ---------------------------------------------------------------- transpose fp32(KxN) -> bf16(NxK)
__global__ void transpose_to_bf16(const float* __restrict__ in, bf16* __restrict__ out,
                                  int K, int N) {
  __shared__ float tile[32][33];
  const int k0 = blockIdx.y * 32, n0 = blockIdx.x * 32;
  const int tx = threadIdx.x, ty = threadIdx.y;
#pragma unroll
  for (int i = ty; i < 32; i += 8)
    tile[i][tx] = in[(size_t)(k0 + i) * N + n0 + tx];
  __syncthreads();
#pragma unroll
  for (int i = ty; i < 32; i += 8)
    out[(size_t)(n0 + i) * K + k0 + tx] = __float2bfloat16(tile[tx][i]);
}

// ---------------------------------------------------------------- layernorm fp32 row -> bf16
__global__ void ln_to_bf16(const float* __restrict__ x, const float* __restrict__ g,
                           const float* __restrict__ bt, bf16* __restrict__ out) {
  const int row = blockIdx.x;
  const float4 v = ((const float4*)(x + (size_t)row * DM))[threadIdx.x];
  float s  = v.x + v.y + v.z + v.w;
  float s2 = v.x * v.x + v.y * v.y + v.z * v.z + v.w * v.w;
#pragma unroll
  for (int o = 32; o > 0; o >>= 1) { s += __shfl_down(s, o); s2 += __shfl_down(s2, o); }
  __shared__ float red[8];
  const int wave = threadIdx.x >> 6, lane = threadIdx.x & 63;
  if (lane == 0) { red[wave] = s; red[4 + wave] = s2; }
  __syncthreads();
  s  = red[0] + red[1] + red[2] + red[3];
  s2 = red[4] + red[5] + red[6] + red[7];
  const float mu  = s * (1.f / DM);
  const float var = s2 * (1.f / DM) - mu * mu;
  const float r   = rsqrtf(var + 1e-5f);
  const float4 gv = ((const float4*)g)[threadIdx.x];
  const float4 bv = ((const float4*)bt)[threadIdx.x];
  bf16* o = out + (size_t)row * DM + threadIdx.x * 4;
  o[0] = __float2bfloat16((v.x - mu) * r * gv.x + bv.x);
  o[1] = __float2bfloat16((v.y - mu) * r * gv.y + bv.y);
  o[2] = __float2bfloat16((v.z - mu) * r * gv.z + bv.z);
  o[3] = __float2bfloat16((v.w - mu) * r * gv.w + bv.w);
}

// ---------------------------------------------------------------- GEMM: C = A(MxK) @ Bt(NxK)^T + bias
// Double-buffered single-barrier K-loop: __syncthreads drains exactly the
// current tile's global_load_lds (issued post-barrier last iter), then next
// tile's loads are issued into the other buffer and overlap this iteration's
// MFMA. TN=64 variant doubles grid size for N=1024 shapes (2 blocks/CU).
enum { EP_BF16 = 0, EP_GELU = 1, EP_RESID = 2 };

template <int MODE, int TN>
__global__ void gemm_bt(const bf16* __restrict__ A, const bf16* __restrict__ Bt,
                        const float* __restrict__ bias, const float* __restrict__ resid,
                        float* __restrict__ Cf, bf16* __restrict__ Cb,
                        int M, int N, int K) {
  constexpr int ABUF = 128 * 32;
  constexpr int BBUF = TN * 32;
  constexpr int NI = TN / 32;  // B sub-tiles per wave
  __shared__ __attribute__((aligned(16))) bf16 As[2 * ABUF];
  __shared__ __attribute__((aligned(16))) bf16 Bs[2 * BBUF];
  const int tid  = threadIdx.x;
  const int wave = tid >> 6, lane = tid & 63;
  const int l16 = lane & 15, lq = lane >> 4;
  const int m0 = blockIdx.x * 128, n0 = blockIdx.y * TN;
  const int wr = (wave >> 1) * 64, wc = (wave & 1) * (TN / 2);

  f32x4 acc[4][NI];
#pragma unroll
  for (int i = 0; i < 4; i++)
#pragma unroll
    for (int j = 0; j < NI; j++) acc[i][j] = 0;

  const int srow = tid >> 2;
  const int scol = (tid & 3) * 8;
  const bf16* ga = A  + (size_t)(m0 + srow) * K + scol;
  const bf16* gb = Bt + (size_t)(n0 + srow) * K + scol;

  // stage tile 0 -> buffer 0
  {
    bf16* la = As + wave * 512;
    bf16* lb = Bs + wave * 512;
    gload_lds16(ga, la);
    gload_lds16(ga + (size_t)64 * K, la + 2048);
    gload_lds16(gb, lb);
    if (TN == 128) gload_lds16(gb + (size_t)64 * K, lb + 2048);
  }

  const int NKT = K >> 5;
  for (int it = 0; it < NKT; ++it) {
    __syncthreads();  // drains tile-it loads (only ones outstanding); aligns waves
    const int cur = it & 1, nxt = cur ^ 1;
    if (it + 1 < NKT) {  // async-stage tile it+1; overlaps MFMA below
      const int kt = (it + 1) << 5;
      bf16* la = As + nxt * ABUF + wave * 512;
      bf16* lb = Bs + nxt * BBUF + wave * 512;
      gload_lds16(ga + kt, la);
      gload_lds16(ga + (size_t)64 * K + kt, la + 2048);
      gload_lds16(gb + kt, lb);
      if (TN == 128) gload_lds16(gb + (size_t)64 * K + kt, lb + 2048);
    }
    bf16x8 af[4], bfr[NI];
#pragma unroll
    for (int mi = 0; mi < 4; mi++)
      af[mi] = *(const bf16x8*)(As + cur * ABUF + (wr + mi * 16 + l16) * 32 + lq * 8);
#pragma unroll
    for (int ni = 0; ni < NI; ni++)
      bfr[ni] = *(const bf16x8*)(Bs + cur * BBUF + (wc + ni * 16 + l16) * 32 + lq * 8);
#pragma unroll
    for (int mi = 0; mi < 4; mi++)
#pragma unroll
      for (int ni = 0; ni < NI; ni++)
        acc[mi][ni] = __builtin_amdgcn_mfma_f32_16x16x32_bf16(af[mi], bfr[ni], acc[mi][ni], 0, 0, 0);
  }

#pragma unroll
  for (int ni = 0; ni < NI; ni++) {
    const int col = n0 + wc + ni * 16 + l16;
    const float bb = bias[col];
#pragma unroll
    for (int mi = 0; mi < 4; mi++) {
#pragma unroll
      for (int r = 0; r < 4; r++) {
        const int row = m0 + wr + mi * 16 + lq * 4 + r;
        const size_t idx = (size_t)row * N + col;
        float v = acc[mi][ni][r] + bb;
        if (MODE == EP_BF16) {
          Cb[idx] = __float2bfloat16(v);
        } else if (MODE == EP_GELU) {
          v = 0.5f * v * (1.0f + erff(v * 0.70710678118654752f));
          Cb[idx] = __float2bfloat16(v);
        } else {
          Cf[idx] = resid[idx] + v;
        }
      }
    }
  }
}

// ---------------------------------------------------------------- flash attention v3 (causal)
#define SCALE_LOG2 0.18033688011112042f  /* 0.125 * log2(e) */

__global__ void flash_attn(const bf16* __restrict__ qkv, bf16* __restrict__ out) {
  const int id = blockIdx.x;
  const int a  = id & 7;
  const int h  = (id >> 3) & 15;
  const int b  = (id >> 7) & 1;
  const int m  = (id >> 8) & 3;
  const int qb = a ^ (((m & 1) * 15) | ((m & 2) << 3));  // {a,15-a,16+a,31-a}

  const int tid = threadIdx.x;
  const int w = tid >> 6, lane = tid & 63;
  const int l16 = lane & 15, lq = lane >> 4;

  const size_t base = (size_t)b * SEQ * 3072;
  const bf16* Qg = qkv + base + (size_t)h * 64;
  const bf16* Kg = qkv + base + 1024 + (size_t)h * 64;
  const ushort* Vg = (const ushort*)(qkv + base + 2048 + (size_t)h * 64);

  __shared__ __attribute__((aligned(16))) bf16 Qs[64][72];
  __shared__ __attribute__((aligned(16))) bf16 Ks[64][72];
  __shared__ __attribute__((aligned(16))) bf16 VTs[64 * 64];
  __shared__ __attribute__((aligned(16))) bf16 Ps[4][16][72];

  const int q0 = qb * 64;
  const int nkb = qb + 1;

  const int krow = tid >> 2, kcol = (tid & 3) * 16;
  const int vd = tid & 63, vc = tid >> 6;
  const int vsw0 = ((vc ^ (vd & 7)) * 8);
  const int vsw1 = (((vc + 4) ^ (vd & 7)) * 8);

  {
    const int r = tid >> 2, c = (tid & 3) * 16;
    const bf16* src = Qg + (size_t)(q0 + r) * 3072 + c;
    *(uint4*)(&Qs[r][c])     = *(const uint4*)(src);
    *(uint4*)(&Qs[r][c + 8]) = *(const uint4*)(src + 8);

    const bf16* ks = Kg + (size_t)krow * 3072 + kcol;
    const uint4 k0 = *(const uint4*)(ks);
    const uint4 k1 = *(const uint4*)(ks + 8);
    ushort va[8], vb[8];
#pragma unroll
    for (int j = 0; j < 8; j++) va[j] = Vg[(size_t)(vc * 8 + j) * 3072 + vd];
#pragma unroll
    for (int j = 0; j < 8; j++) vb[j] = Vg[(size_t)((vc + 4) * 8 + j) * 3072 + vd];
    *(uint4*)(&Ks[krow][kcol])     = k0;
    *(uint4*)(&Ks[krow][kcol + 8]) = k1;
    uint4 wa, wb;
    wa.x = (uint)va[0] | ((uint)va[1] << 16); wa.y = (uint)va[2] | ((uint)va[3] << 16);
    wa.z = (uint)va[4] | ((uint)va[5] << 16); wa.w = (uint)va[6] | ((uint)va[7] << 16);
    wb.x = (uint)vb[0] | ((uint)vb[1] << 16); wb.y = (uint)vb[2] | ((uint)vb[3] << 16);
    wb.z = (uint)vb[4] | ((uint)vb[5] << 16); wb.w = (uint)vb[6] | ((uint)vb[7] << 16);
    *(uint4*)(&VTs[vd * 64 + vsw0]) = wa;
    *(uint4*)(&VTs[vd * 64 + vsw1]) = wb;
  }
  __syncthreads();

  const bf16x8 qf0 = *(const bf16x8*)(&Qs[w * 16 + l16][lq * 8]);
  const bf16x8 qf1 = *(const bf16x8*)(&Qs[w * 16 + l16][32 + lq * 8]);

  f32x4 oacc[4];
#pragma unroll
  for (int i = 0; i < 4; i++) oacc[i] = 0;
  float lsum[4] = {0.f, 0.f, 0.f, 0.f};

  uint4 kr0, kr1;
  ushort va[8], vb[8];
  const int sw0 = (lq ^ (l16 & 7)) * 8;
  const int sw1 = ((4 + lq) ^ (l16 & 7)) * 8;

  for (int kb = 0; kb < nkb; ++kb) {
    const bool more = (kb + 1 < nkb);

    if (more) {
      const size_t koff = (size_t)((kb + 1) * 64);
      const bf16* ks = Kg + (koff + krow) * 3072 + kcol;
      kr0 = *(const uint4*)(ks);
      kr1 = *(const uint4*)(ks + 8);
#pragma unroll
      for (int j = 0; j < 8; j++) va[j] = Vg[(koff + vc * 8 + j) * 3072 + vd];
#pragma unroll
      for (int j = 0; j < 8; j++) vb[j] = Vg[(koff + (vc + 4) * 8 + j) * 3072 + vd];
    }

    f32x4 sacc[4];
#pragma unroll
    for (int nt = 0; nt < 4; nt++) sacc[nt] = 0;
#pragma unroll
    for (int nt = 0; nt < 4; nt++) {
      const bf16x8 kf0 = *(const bf16x8*)(&Ks[nt * 16 + l16][lq * 8]);
      const bf16x8 kf1 = *(const bf16x8*)(&Ks[nt * 16 + l16][32 + lq * 8]);
      sacc[nt] = __builtin_amdgcn_mfma_f32_16x16x32_bf16(qf0, kf0, sacc[nt], 0, 0, 0);
      sacc[nt] = __builtin_amdgcn_mfma_f32_16x16x32_bf16(qf1, kf1, sacc[nt], 0, 0, 0);
    }

    const bool diag = (kb == qb);
#pragma unroll
    for (int r = 0; r < 4; r++) {
      float e[4];
#pragma unroll
      for (int nt = 0; nt < 4; nt++) {
        float sv = sacc[nt][r] * SCALE_LOG2;
        sv = fminf(sv, 88.f);
        if (diag && (nt * 16 + l16 > w * 16 + lq * 4 + r)) sv = -1e30f;
        e[nt] = exp2f(sv);
        Ps[w][lq * 4 + r][nt * 16 + l16] = __float2bfloat16(e[nt]);
      }
      lsum[r] += (e[0] + e[1]) + (e[2] + e[3]);
    }

    const bf16x8 pf0 = *(const bf16x8*)(&Ps[w][l16][lq * 8]);
    const bf16x8 pf1 = *(const bf16x8*)(&Ps[w][l16][32 + lq * 8]);
#pragma unroll
    for (int dt = 0; dt < 4; dt++) {
      const int d = dt * 16 + l16;
      const bf16x8 vf0 = *(const bf16x8*)(&VTs[d * 64 + sw0]);
      const bf16x8 vf1 = *(const bf16x8*)(&VTs[d * 64 + sw1]);
      oacc[dt] = __builtin_amdgcn_mfma_f32_16x16x32_bf16(pf0, vf0, oacc[dt], 0, 0, 0);
      oacc[dt] = __builtin_amdgcn_mfma_f32_16x16x32_bf16(pf1, vf1, oacc[dt], 0, 0, 0);
    }

    if (more) {
      __syncthreads();
      *(uint4*)(&Ks[krow][kcol])     = kr0;
      *(uint4*)(&Ks[krow][kcol + 8]) = kr1;
      uint4 wa, wb;
      wa.x = (uint)va[0] | ((uint)va[1] << 16); wa.y = (uint)va[2] | ((uint)va[3] << 16);
      wa.z = (uint)va[4] | ((uint)va[5] << 16); wa.w = (uint)va[6] | ((uint)va[7] << 16);
      wb.x = (uint)vb[0] | ((uint)vb[1] << 16); wb.y = (uint)vb[2] | ((uint)vb[3] << 16);
      wb.z = (uint)vb[4] | ((uint)vb[5] << 16); wb.w = (uint)vb[6] | ((uint)vb[7] << 16);
      *(uint4*)(&VTs[vd * 64 + vsw0]) = wa;
      *(uint4*)(&VTs[vd * 64 + vsw1]) = wb;
      __syncthreads();
    }
  }

#pragma unroll
  for (int r = 0; r < 4; r++) {
    float l = lsum[r];
    l += __shfl_xor(l, 1);
    l += __shfl_xor(l, 2);
    l += __shfl_xor(l, 4);
    l += __shfl_xor(l, 8);
    lsum[r] = 1.f / l;
  }
#pragma unroll
  for (int dt = 0; dt < 4; dt++)
#pragma unroll
    for (int r = 0; r < 4; r++) {
      const int qrow = q0 + w * 16 + lq * 4 + r;
      const float v = oacc[dt][r] * lsum[r];
      out[(size_t)(b * SEQ + qrow) * DM + h * 64 + dt * 16 + l16] = __float2bfloat16(v);
    }
}

// ---------------------------------------------------------------- launch
extern "C" void kernel_launch(void* const* d_in, const int* in_sizes, int n_in,
                              void* d_out, int out_size, void* d_ws, size_t ws_size,
                              hipStream_t stream) {
  const float* x     = (const float*)d_in[0];
  const float* w_qkv = (const float*)d_in[1];
  const float* b_qkv = (const float*)d_in[2];
  const float* w_fc  = (const float*)d_in[3];
  const float* b_fc  = (const float*)d_in[4];
  const float* ln1_g = (const float*)d_in[5];
  const float* ln1_b = (const float*)d_in[6];
  const float* ln2_g = (const float*)d_in[7];
  const float* ln2_b = (const float*)d_in[8];
  const float* w1    = (const float*)d_in[9];
  const float* b1    = (const float*)d_in[10];
  const float* w2    = (const float*)d_in[11];
  const float* b2    = (const float*)d_in[12];
  float* out = (float*)d_out;

  char* ws    = (char*)d_ws;
  float* x2   = (float*)(ws);                       // 16 MB fp32 post-attn residual
  bf16* big   = (bf16*)(ws + (size_t)(16 << 20));   // 32 MB: qkv (24MB) then fc1 out (32MB)
  bf16* small = (bf16*)(ws + (size_t)(48 << 20));   // 8 MB: h1 / attn-out / h2
  bf16* wT    = (bf16*)(ws + (size_t)(56 << 20));   // 8 MB: transposed weight scratch

  const dim3 tb(32, 8);

  ln_to_bf16<<<dim3(4096), dim3(256), 0, stream>>>(x, ln1_g, ln1_b, small);
  transpose_to_bf16<<<dim3(96, 32), tb, 0, stream>>>(w_qkv, wT, 1024, 3072);
  gemm_bt<EP_BF16, 128><<<dim3(32, 24), dim3(256), 0, stream>>>(
      small, wT, b_qkv, nullptr, nullptr, big, 4096, 3072, 1024);
  flash_attn<<<dim3(1024), dim3(256), 0, stream>>>(big, small);
  transpose_to_bf16<<<dim3(32, 32), tb, 0, stream>>>(w_fc, wT, 1024, 1024);
  gemm_bt<EP_RESID, 64><<<dim3(32, 16), dim3(256), 0, stream>>>(
      small, wT, b_fc, x, x2, nullptr, 4096, 1024, 1024);
  ln_to_bf16<<<dim3(4096), dim3(256), 0, stream>>>(x2, ln2_g, ln2_b, small);
  transpose_to_bf16<<<dim3(128, 32), tb, 0, stream>>>(w1, wT, 1024, 4096);
  gemm_bt<EP_GELU, 128><<<dim3(32, 32), dim3(256), 0, stream>>>(
      small, wT, b1, nullptr, nullptr, big, 4096, 4096, 1024);
  transpose_to_bf16<<<dim3(32, 128), tb, 0, stream>>>(w2, wT, 4096, 1024);
  gemm_bt<EP_RESID, 64><<<dim3(32, 16), dim3(256), 0, stream>>>(
      big, wT, b2, x2, out, nullptr, 4096, 1024, 4096);
}